// Round 11
// baseline (426.350 us; speedup 1.0000x reference)
//
#include <hip/hip_runtime.h>
#include <stdint.h>

// Problem constants
#define BB 4
#define LL 2048
#define QQ 16293
#define RR 24
#define DD 32
#define SS 128
#define NLAYER 8
#define OUTW 1792
#define TT0 2047              // length of x after embedding (L-1)
#define MROWS (BB*OUTW)       // 7168
#define NPAD 16384            // padded Q for GEMM tiles
#define WCH 28                // skip rows per fused-layer block (64 blocks/batch)

typedef float v4f __attribute__((ext_vector_type(4)));
typedef short v8s __attribute__((ext_vector_type(8)));

static __device__ __forceinline__ unsigned short f2bf(float x) {
  unsigned int u = __float_as_uint(x);
  unsigned int r = (u + 0x7fffu + ((u >> 16) & 1u)) >> 16;
  return (unsigned short)r;
}

static __device__ __forceinline__ float fast_sigmoid(float z) {
  return __builtin_amdgcn_rcpf(1.0f + __expf(-z));
}
static __device__ __forceinline__ float fast_tanh(float z) {
  return 1.0f - 2.0f * __builtin_amdgcn_rcpf(1.0f + __expf(2.0f * z));
}

// ---------------------------------------------------------------------------
// Fused: embedding + 8 WaveNet layers + skip accumulation.
// v2 change (ONLY the skip phase): wave w<14 owns skip rows {2w,2w+1},
// lane owns cols {2*lane, 2*lane+1}. Weights via coalesced float2 VECTOR
// loads (512B/wave, VMEM pipe) instead of 32 s_load_dwordx8/wave/layer on
// the scalar pipe; 128 fma/thread at full lane balance (was 256 at 44%).
// Conv / residual / embed phases unchanged.
// ---------------------------------------------------------------------------
__global__ __launch_bounds__(1024) void fused_layers_kernel(
    const int* __restrict__ idx, const float* __restrict__ preW,
    const float* __restrict__ filtW, const float* __restrict__ gateW,
    const float* __restrict__ resW, const float* __restrict__ skipW,
    float* __restrict__ skip_out) {
  int b = blockIdx.y;
  int j0 = blockIdx.x * WCH;
  int lane = (int)(threadIdx.x & 63);
  int w = __builtin_amdgcn_readfirstlane((int)(threadIdx.x >> 6));

  __shared__ float x_t[2][RR][66];   // col-major: x_t[buf][r][l]
  __shared__ float out_s[64][33];

  for (int z = (int)threadIdx.x; z < 2 * RR * 2; z += 1024) {
    int bu = z & 1;
    int cc = 64 + ((z >> 1) & 1);
    int r = z >> 2;
    x_t[bu][r][cc] = 0.f;
  }

  int tbase = j0 + 247;
  if (w < 12) {
    int t = tbase + lane;
    if (t > TT0 - 1) t = TT0 - 1;
    int i0 = idx[b * LL + t];
    int i1 = idx[b * LL + t + 1];
    const float* p0 = preW + (size_t)i0 * RR + 2 * w;
    const float* p1 = preW + (size_t)QQ * RR + (size_t)i1 * RR + 2 * w;
#pragma unroll
    for (int rr = 0; rr < 2; ++rr)
      x_t[0][2 * w + rr][lane] = p0[rr] + p1[rr];
  }

  float sk00 = 0.f, sk01 = 0.f, sk10 = 0.f, sk11 = 0.f;

  __syncthreads();

  for (int i = 0; i < NLAYER; ++i) {
    int cur = i & 1, nxt = cur ^ 1;
    int lmax = 62 - i;

    // ---- conv phase (unchanged): d-slice [2w,2w+2) per wave, s_load weights
    float xa[RR], xb[RR];
#pragma unroll
    for (int r = 0; r < RR; ++r) {
      xa[r] = x_t[cur][r][lane];
      xb[r] = x_t[cur][r][lane + 1];
    }
    const float* Fw = filtW + (size_t)i * 2 * RR * DD;
    const float* Gw = gateW + (size_t)i * 2 * RR * DD;
    float zf[2], zg[2];
#pragma unroll
    for (int dd = 0; dd < 2; ++dd) { zf[dd] = 0.f; zg[dd] = 0.f; }
#pragma unroll
    for (int r = 0; r < RR; ++r) {
#pragma unroll
      for (int dd = 0; dd < 2; ++dd) {
        int d = w * 2 + dd;
        zf[dd] = fmaf(xa[r], Fw[r * DD + d], zf[dd]);
        zf[dd] = fmaf(xb[r], Fw[RR * DD + r * DD + d], zf[dd]);
        zg[dd] = fmaf(xa[r], Gw[r * DD + d], zg[dd]);
        zg[dd] = fmaf(xb[r], Gw[RR * DD + r * DD + d], zg[dd]);
      }
    }
    if (lane <= lmax) {
#pragma unroll
      for (int dd = 0; dd < 2; ++dd)
        out_s[lane][w * 2 + dd] = fast_tanh(zf[dd]) * fast_sigmoid(zg[dd]);
    }
    __syncthreads();

    // ---- skip phase v2: wave w<14 -> rows {2w,2w+1}; lane -> cols {2l,2l+1}
    if (w < 14) {
      const float2* S2 = (const float2*)(skipW + (size_t)i * DD * SS);
      int jr = 2 * w + 7 - i;
#pragma unroll
      for (int d = 0; d < DD; ++d) {
        float o0 = out_s[jr][d];
        float o1 = out_s[jr + 1][d];
        float2 wv = S2[d * 64 + lane];   // 512B coalesced per wave
        sk00 = fmaf(o0, wv.x, sk00);
        sk01 = fmaf(o0, wv.y, sk01);
        sk10 = fmaf(o1, wv.x, sk10);
        sk11 = fmaf(o1, wv.y, sk11);
      }
    }

    // ---- residual phase (unchanged)
    if (w < 12 && lane <= lmax) {
      const float* Rw = resW + (size_t)i * DD * RR;
#pragma unroll
      for (int rr = 0; rr < 2; ++rr) {
        int r = w * 2 + rr;
        float acc = x_t[cur][r][lane + 1];
#pragma unroll
        for (int d = 0; d < DD; ++d)
          acc = fmaf(out_s[lane][d], Rw[d * RR + r], acc);
        x_t[nxt][r][lane] = acc;
      }
    }
    __syncthreads();
  }

  // ---- write skip_sum: rows {2w,2w+1}, cols {2*lane,2*lane+1} coalesced
  if (w < 14) {
    size_t base = ((size_t)b * OUTW + j0 + 2 * w) * SS + 2 * lane;
    float2 v0; v0.x = sk00; v0.y = sk01;
    float2 v1; v1.x = sk10; v1.y = sk11;
    *(float2*)(skip_out + base) = v0;
    *(float2*)(skip_out + base + SS) = v1;
  }
}

// ---------------------------------------------------------------------------
// h1 = relu(relu(skip_sum) @ post_W1), stored bf16  [7168][128] (unchanged)
// ---------------------------------------------------------------------------
__global__ __launch_bounds__(256) void h1_kernel(const float* __restrict__ skip_sum,
                                                 const float* __restrict__ W1,
                                                 unsigned short* __restrict__ h1) {
  int m0 = blockIdx.x * 32;
  int tc = threadIdx.x & 31;
  int tr = threadIdx.x >> 5;
  __shared__ float h_s[32][128];
#pragma unroll
  for (int it = 0; it < 16; ++it) {
    int lin = it * 256 + (int)threadIdx.x;
    int rrow = lin >> 7, d = lin & 127;
    float v = skip_sum[(size_t)(m0 + rrow) * SS + d];
    h_s[rrow][d] = v > 0.f ? v : 0.f;
  }
  __syncthreads();

  float acc[4][4];
#pragma unroll
  for (int rr = 0; rr < 4; ++rr)
#pragma unroll
    for (int c = 0; c < 4; ++c) acc[rr][c] = 0.f;

#pragma unroll 4
  for (int d = 0; d < 128; ++d) {
    float4 wv = *(const float4*)(W1 + (size_t)d * SS + tc * 4);
#pragma unroll
    for (int rr = 0; rr < 4; ++rr) {
      float hv = h_s[tr * 4 + rr][d];
      acc[rr][0] = fmaf(hv, wv.x, acc[rr][0]);
      acc[rr][1] = fmaf(hv, wv.y, acc[rr][1]);
      acc[rr][2] = fmaf(hv, wv.z, acc[rr][2]);
      acc[rr][3] = fmaf(hv, wv.w, acc[rr][3]);
    }
  }
#pragma unroll
  for (int rr = 0; rr < 4; ++rr) {
    int row = m0 + tr * 4 + rr;
    ushort4 u;
    u.x = f2bf(fmaxf(acc[rr][0], 0.f));
    u.y = f2bf(fmaxf(acc[rr][1], 0.f));
    u.z = f2bf(fmaxf(acc[rr][2], 0.f));
    u.w = f2bf(fmaxf(acc[rr][3], 0.f));
    *(ushort4*)(h1 + (size_t)row * SS + tc * 4) = u;
  }
}

// ---------------------------------------------------------------------------
// W2T: transpose post_W2 [128][16293] -> bf16 [16384][128], zero-padded
// ---------------------------------------------------------------------------
__global__ __launch_bounds__(256) void w2t_kernel(const float* __restrict__ W2,
                                                  unsigned short* __restrict__ W2T) {
  int n0 = blockIdx.x * 64;
  __shared__ float t_s[64][129];
#pragma unroll
  for (int it = 0; it < 32; ++it) {
    int lin = it * 256 + (int)threadIdx.x;
    int k = lin >> 6, nn = lin & 63;
    int n = n0 + nn;
    t_s[nn][k] = (n < QQ) ? W2[(size_t)k * QQ + n] : 0.f;
  }
  __syncthreads();
#pragma unroll
  for (int it = 0; it < 4; ++it) {
    int lin = it * 256 + (int)threadIdx.x;
    int nn = lin >> 4, slot = lin & 15;
    v8s val;
#pragma unroll
    for (int jj = 0; jj < 8; ++jj) val[jj] = (short)f2bf(t_s[nn][slot * 8 + jj]);
    *(v8s*)(W2T + ((size_t)(n0 + nn)) * 128 + slot * 8) = val;
  }
}

// ---------------------------------------------------------------------------
// logits = h1 @ W2 (bf16 MFMA, fp32 accum). EXACT v1 (272.7us config, nt
// stores). Launched TWICE this round so it lands in rocprof top-5: need
// WRITE_SIZE (amplification?), FETCH_SIZE (allocate?), MfmaUtil/Occupancy
// (serialization?) for the real kernel. Deterministic: writes same data.
// ---------------------------------------------------------------------------
struct GemmLds {
  union {
    struct { unsigned short A_s[128 * 128]; unsigned short B_s[128 * 128]; } ab;
    float c_s[128][132];
  };
};

__global__ __launch_bounds__(256) void gemm_kernel(const unsigned short* __restrict__ A,
                                                   const unsigned short* __restrict__ Bm,
                                                   float* __restrict__ Cc) {
  __shared__ GemmLds sh;
  unsigned short* A_s = sh.ab.A_s;
  unsigned short* B_s = sh.ab.B_s;
  int m0 = blockIdx.y * 128;
  int n0 = blockIdx.x * 128;
  int tid = threadIdx.x;

#pragma unroll
  for (int it = 0; it < 8; ++it) {
    int lin = it * 256 + tid;
    int row = lin >> 4, slot = lin & 15;
    int sw = slot ^ (row & 7);
    uint4 va = *(const uint4*)(A + ((size_t)(m0 + row)) * 128 + slot * 8);
    *(uint4*)(A_s + row * 128 + sw * 8) = va;
    uint4 vb = *(const uint4*)(Bm + ((size_t)(n0 + row)) * 128 + slot * 8);
    *(uint4*)(B_s + row * 128 + sw * 8) = vb;
  }
  __syncthreads();

  int lane = tid & 63;
  int w = tid >> 6;
  int wm = (w >> 1) * 64, wn = (w & 1) * 64;
  int lr = lane & 15, g = lane >> 4;

  v4f acc[4][4];
#pragma unroll
  for (int mf = 0; mf < 4; ++mf)
#pragma unroll
    for (int nf = 0; nf < 4; ++nf) {
      v4f z = {0.f, 0.f, 0.f, 0.f};
      acc[mf][nf] = z;
    }

#pragma unroll
  for (int ks = 0; ks < 4; ++ks) {
    int kg = ks * 4 + g;
    v8s a[4], bfr[4];
#pragma unroll
    for (int mf = 0; mf < 4; ++mf) {
      int row = wm + mf * 16 + lr;
      a[mf] = *(v8s*)(A_s + row * 128 + ((kg ^ (row & 7)) * 8));
    }
#pragma unroll
    for (int nf = 0; nf < 4; ++nf) {
      int row = wn + nf * 16 + lr;
      bfr[nf] = *(v8s*)(B_s + row * 128 + ((kg ^ (row & 7)) * 8));
    }
#pragma unroll
    for (int mf = 0; mf < 4; ++mf)
#pragma unroll
      for (int nf = 0; nf < 4; ++nf)
        acc[mf][nf] = __builtin_amdgcn_mfma_f32_16x16x32_bf16(a[mf], bfr[nf], acc[mf][nf], 0, 0, 0);
  }

  // ---- epilogue: acc -> LDS transpose, then nt v4f stores (v1 exact)
  __syncthreads();
#pragma unroll
  for (int mf = 0; mf < 4; ++mf)
#pragma unroll
    for (int reg = 0; reg < 4; ++reg) {
      int row = wm + mf * 16 + g * 4 + reg;
#pragma unroll
      for (int nf = 0; nf < 4; ++nf)
        sh.c_s[row][wn + nf * 16 + lr] = acc[mf][nf][reg];
    }
  __syncthreads();

  int slot = tid & 31;
  int rsub = tid >> 5;
  bool edge = (n0 + 128 > QQ);
#pragma unroll
  for (int it = 0; it < 16; ++it) {
    int row = it * 8 + rsub;
    int n = n0 + slot * 4;
    v4f v = *(v4f*)(&sh.c_s[row][slot * 4]);
    float* crow = Cc + (size_t)(m0 + row) * QQ;
    if (!edge) {
      __builtin_nontemporal_store(v, (v4f*)(crow + n));
    } else {
      if (n + 3 < QQ) {
        __builtin_nontemporal_store(v, (v4f*)(crow + n));
      } else {
        if (n + 0 < QQ) crow[n + 0] = v.x;
        if (n + 1 < QQ) crow[n + 1] = v.y;
        if (n + 2 < QQ) crow[n + 2] = v.z;
        if (n + 3 < QQ) crow[n + 3] = v.w;
      }
    }
  }
}

// ---------------------------------------------------------------------------
extern "C" void kernel_launch(void* const* d_in, const int* in_sizes, int n_in,
                              void* d_out, int out_size, void* d_ws, size_t ws_size,
                              hipStream_t stream) {
  (void)in_sizes; (void)n_in; (void)out_size; (void)ws_size;
  const int*   idx   = (const int*)d_in[0];
  const float* preW  = (const float*)d_in[1];
  const float* filtW = (const float*)d_in[2];
  const float* gateW = (const float*)d_in[3];
  const float* resW  = (const float*)d_in[4];
  const float* skipW = (const float*)d_in[5];
  const float* W1    = (const float*)d_in[6];
  const float* W2    = (const float*)d_in[7];
  float* out = (float*)d_out;

  char* ws = (char*)d_ws;
  float* skip = (float*)(ws);                              // 3,670,016 B
  unsigned short* h1  = (unsigned short*)(ws + 3670016);   // 1,835,008 B
  unsigned short* W2T = (unsigned short*)(ws + 5505024);   // 4,194,304 B  (~9.7 MB)

  w2t_kernel<<<dim3(NPAD / 64), 256, 0, stream>>>(W2, W2T);
  fused_layers_kernel<<<dim3(OUTW / WCH, BB), 1024, 0, stream>>>(idx, preW, filtW, gateW,
                                                                 resW, skipW, skip);
  h1_kernel<<<dim3(MROWS / 32), 256, 0, stream>>>(skip, W1, h1);
  // Launched twice (deterministic, identical output) so gemm lands in the
  // rocprof top-5 this round — attribution, removed next round.
  gemm_kernel<<<dim3(NPAD / 128, MROWS / 128), 256, 0, stream>>>(h1, W2T, out);
  gemm_kernel<<<dim3(NPAD / 128, MROWS / 128), 256, 0, stream>>>(h1, W2T, out);
}